// Round 1
// baseline (446.166 us; speedup 1.0000x reference)
//
#include <hip/hip_runtime.h>
#include <math.h>

// Triangle attention, fp32 baseline.
// Shapes: B=1, S=256 (outer rows), Q=K=256, C=128, H=4, D=32.
// ws layout: qb | kb | vb | gb, each 65536x128 fp32 (33.55 MB) -> 134 MB total.
// o_gated goes into d_out; final GEMM is done in-place on d_out.

#define QSCALE 0.17677669529663689f  // 1/sqrt(32)

// XOR swizzle: float index of the i4-th 4-float group of `row` (row length 128 floats).
// Breaks stride-128 bank conflicts for both row-indexed and col-indexed reads.
__device__ __forceinline__ int swz(int row, int i4) {
    return row * 128 + ((i4 ^ ((row >> 3) & 7)) << 2);
}

// ---------------- Kernel A: 4-way projection GEMM ----------------
// block = 256 threads, 64 rows per block, 1024 blocks.
// pid 0=q (scale), 1=g (sigmoid(x+bg)), 2=k, 3=v.
__global__ __launch_bounds__(256) void proj_kernel(
    const float* __restrict__ q_x, const float* __restrict__ kv_x,
    const float* __restrict__ wq, const float* __restrict__ wk,
    const float* __restrict__ wv, const float* __restrict__ wg,
    const float* __restrict__ bg,
    float* __restrict__ qb, float* __restrict__ kbuf,
    float* __restrict__ vbuf, float* __restrict__ gb)
{
    extern __shared__ float smem[];
    float* xl = smem;            // 64 x 128 (swizzled)
    float* wl = smem + 64 * 128; // 64 x 128 (swizzled), half of a weight at a time
    const int t = threadIdx.x;
    const int r0g = blockIdx.x * 64;
    const int tr = t >> 4, tc = t & 15;
    const int r0 = tr * 4;

    for (int phase = 0; phase < 2; ++phase) {
        __syncthreads();  // prior compute done before xl overwrite
        const float* xsrc = phase ? kv_x : q_x;
        #pragma unroll
        for (int j = 0; j < 8; ++j) {
            int f = t + 256 * j;
            int row = f >> 5, c4 = f & 31;
            float4 val = *(const float4*)(xsrc + (size_t)(r0g + row) * 128 + c4 * 4);
            *(float4*)(xl + swz(row, c4)) = val;
        }
        for (int sub = 0; sub < 2; ++sub) {
            const int pid = phase * 2 + sub;
            const float* w = (pid == 0) ? wq : (pid == 1) ? wg : (pid == 2) ? wk : wv;
            float* dst = (pid == 0) ? qb : (pid == 1) ? gb : (pid == 2) ? kbuf : vbuf;
            for (int half = 0; half < 2; ++half) {
                __syncthreads();  // prior compute done before wl overwrite (also covers xl stores)
                #pragma unroll
                for (int j = 0; j < 8; ++j) {
                    int f = t + 256 * j;
                    int row = f >> 5, c4 = f & 31;
                    float4 val = *(const float4*)(w + (size_t)(half * 64 + row) * 128 + c4 * 4);
                    *(float4*)(wl + swz(row, c4)) = val;
                }
                __syncthreads();
                float acc[4][4];
                #pragma unroll
                for (int rr = 0; rr < 4; ++rr)
                    #pragma unroll
                    for (int cc = 0; cc < 4; ++cc) acc[rr][cc] = 0.f;
                #pragma unroll 4
                for (int i4 = 0; i4 < 32; ++i4) {
                    float4 xa[4], wb[4];
                    #pragma unroll
                    for (int rr = 0; rr < 4; ++rr)
                        xa[rr] = *(const float4*)(xl + swz(r0 + rr, i4));
                    #pragma unroll
                    for (int cc = 0; cc < 4; ++cc)
                        wb[cc] = *(const float4*)(wl + swz(tc * 4 + cc, i4));
                    #pragma unroll
                    for (int rr = 0; rr < 4; ++rr)
                        #pragma unroll
                        for (int cc = 0; cc < 4; ++cc)
                            acc[rr][cc] += xa[rr].x * wb[cc].x + xa[rr].y * wb[cc].y
                                         + xa[rr].z * wb[cc].z + xa[rr].w * wb[cc].w;
                }
                const int cbase = half * 64 + tc * 4;
                #pragma unroll
                for (int rr = 0; rr < 4; ++rr) {
                    float v0 = acc[rr][0], v1 = acc[rr][1], v2 = acc[rr][2], v3 = acc[rr][3];
                    if (pid == 0) {
                        v0 *= QSCALE; v1 *= QSCALE; v2 *= QSCALE; v3 *= QSCALE;
                    } else if (pid == 1) {
                        v0 = 1.f / (1.f + __expf(-(v0 + bg[cbase + 0])));
                        v1 = 1.f / (1.f + __expf(-(v1 + bg[cbase + 1])));
                        v2 = 1.f / (1.f + __expf(-(v2 + bg[cbase + 2])));
                        v3 = 1.f / (1.f + __expf(-(v3 + bg[cbase + 3])));
                    }
                    float4 outv = make_float4(v0, v1, v2, v3);
                    *(float4*)(dst + (size_t)(r0g + r0 + rr) * 128 + cbase) = outv;
                }
            }
        }
    }
}

// ---------------- Kernel B: per-(s,h) attention ----------------
// grid = (H=4, S=256), block = 256 threads (one q-row per thread).
// Online softmax in chunks of 4 keys; k/v head-slab staged in LDS.
// Writes gated output into og (= d_out) at [s*256+q][h*32+d].
__global__ __launch_bounds__(256) void attn_kernel(
    const float* __restrict__ qb, const float* __restrict__ kbuf,
    const float* __restrict__ vbuf, const float* __restrict__ gb,
    const float* __restrict__ bias1, const float* __restrict__ bias2,
    float* __restrict__ og)
{
    extern __shared__ float smem[];
    float* kl = smem;           // 256 x 32
    float* vl = smem + 8192;    // 256 x 32
    float* b2s = smem + 16384;  // 256
    const int h = blockIdx.x;
    const int s = blockIdx.y;
    const int t = threadIdx.x;
    const size_t base = (size_t)s << 15;  // s*256*128

    #pragma unroll
    for (int j = 0; j < 8; ++j) {
        int f = t + 256 * j;
        int kk = f >> 3, c4 = f & 7;
        *(float4*)(kl + kk * 32 + c4 * 4) =
            *(const float4*)(kbuf + base + (size_t)kk * 128 + h * 32 + c4 * 4);
        *(float4*)(vl + kk * 32 + c4 * 4) =
            *(const float4*)(vbuf + base + (size_t)kk * 128 + h * 32 + c4 * 4);
    }
    b2s[t] = bias2[s * 256 + t];

    float qr[32];
    const float* qp = qb + base + (size_t)t * 128 + h * 32;
    #pragma unroll
    for (int j = 0; j < 8; ++j) {
        float4 v = *(const float4*)(qp + 4 * j);
        qr[4*j] = v.x; qr[4*j+1] = v.y; qr[4*j+2] = v.z; qr[4*j+3] = v.w;
    }
    __syncthreads();

    const float4* b1p = (const float4*)(bias1 + (size_t)h * 65536 + (size_t)t * 256);
    float m = -1e30f, l = 0.f;
    float o[32];
    #pragma unroll
    for (int d = 0; d < 32; ++d) o[d] = 0.f;

    for (int k0 = 0; k0 < 256; k0 += 4) {
        float4 b1 = b1p[k0 >> 2];
        float sc[4];
        #pragma unroll
        for (int u = 0; u < 4; ++u) {
            const float* kr = kl + (k0 + u) * 32;
            float a0 = 0.f, a1 = 0.f, a2 = 0.f, a3 = 0.f;
            #pragma unroll
            for (int d4 = 0; d4 < 8; ++d4) {
                float4 kv4 = *(const float4*)(kr + 4 * d4);
                a0 += qr[4*d4+0] * kv4.x;
                a1 += qr[4*d4+1] * kv4.y;
                a2 += qr[4*d4+2] * kv4.z;
                a3 += qr[4*d4+3] * kv4.w;
            }
            sc[u] = (a0 + a1) + (a2 + a3);
        }
        sc[0] += b1.x + b2s[k0 + 0];
        sc[1] += b1.y + b2s[k0 + 1];
        sc[2] += b1.z + b2s[k0 + 2];
        sc[3] += b1.w + b2s[k0 + 3];
        float mloc = fmaxf(fmaxf(sc[0], sc[1]), fmaxf(sc[2], sc[3]));
        float mn = fmaxf(m, mloc);
        float corr = __expf(m - mn);
        float p0 = __expf(sc[0] - mn);
        float p1 = __expf(sc[1] - mn);
        float p2 = __expf(sc[2] - mn);
        float p3 = __expf(sc[3] - mn);
        l = l * corr + ((p0 + p1) + (p2 + p3));
        const float* vr = vl + k0 * 32;
        #pragma unroll
        for (int d4 = 0; d4 < 8; ++d4) {
            float4 va = *(const float4*)(vr + 4 * d4);
            float4 vb2 = *(const float4*)(vr + 32 + 4 * d4);
            float4 vc = *(const float4*)(vr + 64 + 4 * d4);
            float4 vd = *(const float4*)(vr + 96 + 4 * d4);
            o[4*d4+0] = o[4*d4+0] * corr + p0*va.x + p1*vb2.x + p2*vc.x + p3*vd.x;
            o[4*d4+1] = o[4*d4+1] * corr + p0*va.y + p1*vb2.y + p2*vc.y + p3*vd.y;
            o[4*d4+2] = o[4*d4+2] * corr + p0*va.z + p1*vb2.z + p2*vc.z + p3*vd.z;
            o[4*d4+3] = o[4*d4+3] * corr + p0*va.w + p1*vb2.w + p2*vc.w + p3*vd.w;
        }
        m = mn;
    }
    float inv = 1.f / l;
    const float* gp = gb + base + (size_t)t * 128 + h * 32;
    float* op = og + base + (size_t)t * 128 + h * 32;
    #pragma unroll
    for (int j = 0; j < 8; ++j) {
        float4 g4 = *(const float4*)(gp + 4 * j);
        float4 r;
        r.x = o[4*j+0] * inv * g4.x;
        r.y = o[4*j+1] * inv * g4.y;
        r.z = o[4*j+2] * inv * g4.z;
        r.w = o[4*j+3] * inv * g4.w;
        *(float4*)(op + 4 * j) = r;
    }
}

// ---------------- Kernel C: in-place output GEMM (+bo) ----------------
__global__ __launch_bounds__(256) void out_kernel(
    float* __restrict__ io, const float* __restrict__ wo, const float* __restrict__ bo)
{
    extern __shared__ float smem[];
    float* xl = smem;
    float* wl = smem + 64 * 128;
    const int t = threadIdx.x;
    const int r0g = blockIdx.x * 64;
    const int tr = t >> 4, tc = t & 15;
    const int r0 = tr * 4;

    #pragma unroll
    for (int j = 0; j < 8; ++j) {
        int f = t + 256 * j;
        int row = f >> 5, c4 = f & 31;
        float4 val = *(const float4*)(io + (size_t)(r0g + row) * 128 + c4 * 4);
        *(float4*)(xl + swz(row, c4)) = val;
    }
    for (int half = 0; half < 2; ++half) {
        __syncthreads();
        #pragma unroll
        for (int j = 0; j < 8; ++j) {
            int f = t + 256 * j;
            int row = f >> 5, c4 = f & 31;
            float4 val = *(const float4*)(wo + (size_t)(half * 64 + row) * 128 + c4 * 4);
            *(float4*)(wl + swz(row, c4)) = val;
        }
        __syncthreads();
        float acc[4][4];
        #pragma unroll
        for (int rr = 0; rr < 4; ++rr)
            #pragma unroll
            for (int cc = 0; cc < 4; ++cc) acc[rr][cc] = 0.f;
        #pragma unroll 4
        for (int i4 = 0; i4 < 32; ++i4) {
            float4 xa[4], wb[4];
            #pragma unroll
            for (int rr = 0; rr < 4; ++rr)
                xa[rr] = *(const float4*)(xl + swz(r0 + rr, i4));
            #pragma unroll
            for (int cc = 0; cc < 4; ++cc)
                wb[cc] = *(const float4*)(wl + swz(tc * 4 + cc, i4));
            #pragma unroll
            for (int rr = 0; rr < 4; ++rr)
                #pragma unroll
                for (int cc = 0; cc < 4; ++cc)
                    acc[rr][cc] += xa[rr].x * wb[cc].x + xa[rr].y * wb[cc].y
                                 + xa[rr].z * wb[cc].z + xa[rr].w * wb[cc].w;
        }
        const int cbase = half * 64 + tc * 4;
        #pragma unroll
        for (int rr = 0; rr < 4; ++rr) {
            float4 outv = make_float4(acc[rr][0] + bo[cbase + 0],
                                      acc[rr][1] + bo[cbase + 1],
                                      acc[rr][2] + bo[cbase + 2],
                                      acc[rr][3] + bo[cbase + 3]);
            *(float4*)(io + (size_t)(r0g + r0 + rr) * 128 + cbase) = outv;
        }
    }
}

extern "C" void kernel_launch(void* const* d_in, const int* in_sizes, int n_in,
                              void* d_out, int out_size, void* d_ws, size_t ws_size,
                              hipStream_t stream)
{
    const float* q_x   = (const float*)d_in[0];
    const float* kv_x  = (const float*)d_in[1];
    const float* bias1 = (const float*)d_in[2];
    const float* bias2 = (const float*)d_in[3];
    const float* wq    = (const float*)d_in[4];
    const float* wk    = (const float*)d_in[5];
    const float* wv    = (const float*)d_in[6];
    const float* wg    = (const float*)d_in[7];
    const float* bg    = (const float*)d_in[8];
    const float* wo    = (const float*)d_in[9];
    const float* bo    = (const float*)d_in[10];
    float* out = (float*)d_out;
    float* ws  = (float*)d_ws;

    const size_t RC = (size_t)65536 * 128;
    float* qb = ws;
    float* kb = ws + RC;
    float* vb = ws + 2 * RC;
    float* gb = ws + 3 * RC;

    proj_kernel<<<1024, 256, 65536, stream>>>(q_x, kv_x, wq, wk, wv, wg, bg, qb, kb, vb, gb);
    attn_kernel<<<dim3(4, 256), 256, 66560, stream>>>(qb, kb, vb, gb, bias1, bias2, out);
    out_kernel<<<1024, 256, 65536, stream>>>(out, wo, bo);
}

// Round 2
// 130.184 us; speedup vs baseline: 3.4272x; 3.4272x over previous
//
#include <hip/hip_runtime.h>
#include <math.h>

typedef _Float16 f16;
typedef _Float16 h4 __attribute__((ext_vector_type(4)));
typedef _Float16 h8 __attribute__((ext_vector_type(8)));
typedef float f32x4 __attribute__((ext_vector_type(4)));

#define QSCALE 0.17677669529663689f  // 1/sqrt(32)

// ---------------- Kernel A: projection GEMM (f16 MFMA) ----------------
// grid (512 row-tiles, 2 phases). phase0: q_x -> {q(scaled), g(sigmoid)};
// phase1: kv_x -> {k, v(transposed store)}. Block 256 thr = 4 waves (2x2),
// out tile 128x128 per weight. LDS: X 32KB + W 32KB, XOR-swizzled 16B chunks.
__global__ __launch_bounds__(256) void proj_mfma(
    const float* __restrict__ q_x, const float* __restrict__ kv_x,
    const float* __restrict__ wq, const float* __restrict__ wk,
    const float* __restrict__ wv, const float* __restrict__ wg,
    const float* __restrict__ bg,
    f16* __restrict__ qb, f16* __restrict__ kb,
    f16* __restrict__ vbT, f16* __restrict__ gb)
{
    __shared__ char lds[65536];
    char* xl = lds;
    char* wl = lds + 32768;
    const int t = threadIdx.x;
    const int lane = t & 63, wave = t >> 6;
    const int wr = wave >> 1, wc = wave & 1;
    const int lo = lane & 15, hi = lane >> 4;
    const int phase = blockIdx.y;
    const int row0 = blockIdx.x * 128;
    const float* xsrc = phase ? kv_x : q_x;

    // stage X tile 128x128 fp32 -> f16 swizzled LDS
    #pragma unroll
    for (int j = 0; j < 16; ++j) {
        int f = t + 256 * j;
        int row = f >> 5, c4 = f & 31;
        float4 v = *(const float4*)(xsrc + (size_t)(row0 + row) * 128 + c4 * 4);
        h4 hv = {(f16)v.x, (f16)v.y, (f16)v.z, (f16)v.w};
        *(h4*)(xl + row * 256 + (((c4 >> 1) ^ (row & 7)) << 4) + ((c4 & 1) << 3)) = hv;
    }

    for (int sub = 0; sub < 2; ++sub) {
        const int pid = phase * 2 + sub;
        const float* w = (pid == 0) ? wq : (pid == 1) ? wg : (pid == 2) ? wk : wv;
        __syncthreads();  // xl ready (sub0) / wl reads done (sub1)
        #pragma unroll
        for (int j = 0; j < 16; ++j) {
            int f = t + 256 * j;
            int row = f >> 5, c4 = f & 31;
            float4 v = *(const float4*)(w + (size_t)row * 128 + c4 * 4);
            h4 hv = {(f16)v.x, (f16)v.y, (f16)v.z, (f16)v.w};
            *(h4*)(wl + row * 256 + (((c4 >> 1) ^ (row & 7)) << 4) + ((c4 & 1) << 3)) = hv;
        }
        __syncthreads();

        f32x4 acc[4][4];
        #pragma unroll
        for (int m = 0; m < 4; ++m)
            #pragma unroll
            for (int n = 0; n < 4; ++n) acc[m][n] = (f32x4){0.f, 0.f, 0.f, 0.f};

        #pragma unroll
        for (int kk = 0; kk < 4; ++kk) {
            const int swz = ((hi + 4 * kk) ^ (lo & 7)) << 4;
            h8 af[4], bf[4];
            #pragma unroll
            for (int m = 0; m < 4; ++m)
                af[m] = *(const h8*)(xl + (lo + 16 * m + 64 * wr) * 256 + swz);
            #pragma unroll
            for (int n = 0; n < 4; ++n)
                bf[n] = *(const h8*)(wl + (lo + 16 * n + 64 * wc) * 256 + swz);
            #pragma unroll
            for (int m = 0; m < 4; ++m)
                #pragma unroll
                for (int n = 0; n < 4; ++n)
                    acc[m][n] = __builtin_amdgcn_mfma_f32_16x16x32_f16(af[m], bf[n], acc[m][n], 0, 0, 0);
        }

        // epilogue: D[row=(l>>4)*4+r][col=l&15]
        #pragma unroll
        for (int n = 0; n < 4; ++n) {
            const int col = 64 * wc + 16 * n + lo;
            const float bgv = (pid == 1) ? bg[col] : 0.f;
            #pragma unroll
            for (int m = 0; m < 4; ++m) {
                if (pid == 3) {
                    // V transposed: vbT[((s*4+h)*32+dh)*256 + key]
                    int rg = row0 + 64 * wr + 16 * m + 4 * hi;
                    int sidx = rg >> 8, key = rg & 255;
                    int hh = col >> 5, dh = col & 31;
                    h4 hv = {(f16)acc[m][n][0], (f16)acc[m][n][1],
                             (f16)acc[m][n][2], (f16)acc[m][n][3]};
                    *(h4*)(vbT + (((size_t)sidx * 4 + hh) * 32 + dh) * 256 + key) = hv;
                } else {
                    f16* dst = (pid == 0) ? qb : (pid == 1) ? gb : kb;
                    #pragma unroll
                    for (int r = 0; r < 4; ++r) {
                        int rg = row0 + 64 * wr + 16 * m + 4 * hi + r;
                        float v = acc[m][n][r];
                        if (pid == 0) v *= QSCALE;
                        else if (pid == 1) v = 1.f / (1.f + __expf(-(v + bgv)));
                        dst[(size_t)rg * 128 + col] = (f16)v;
                    }
                }
            }
        }
    }
}

// ---------------- Kernel B: attention (f16 MFMA, flash-style) ----------------
// grid (H=4, S=256), block 256 = 4 independent waves, each owning 64 q-rows.
// k-tiles of 32; bias1+bias2 as MFMA C-init; softmax via width-16 shfl_xor;
// P through per-wave swizzled LDS (write u16 D-layout, read b128 A-frags).
__global__ __launch_bounds__(256) void attn_mfma(
    const f16* __restrict__ qb, const f16* __restrict__ kb,
    const f16* __restrict__ vbT, const f16* __restrict__ gb,
    const float* __restrict__ bias1, const float* __restrict__ bias2,
    f16* __restrict__ ob)
{
    __shared__ char plds[16384];
    const int h = blockIdx.x, s = blockIdx.y;
    const int t = threadIdx.x, wave = t >> 6, lane = t & 63;
    const int lo = lane & 15, hi = lane >> 4;
    char* pw = plds + wave * 4096;
    const size_t rowbase = (size_t)s * 256;
    const int q0 = wave * 64;

    h8 qf[4];
    #pragma unroll
    for (int m = 0; m < 4; ++m)
        qf[m] = *(const h8*)(qb + (rowbase + q0 + 16 * m + lo) * 128 + h * 32 + 8 * hi);

    f32x4 Oa[4][2];
    float mr[4][4], lr[4][4];
    #pragma unroll
    for (int m = 0; m < 4; ++m) {
        #pragma unroll
        for (int n = 0; n < 2; ++n) Oa[m][n] = (f32x4){0.f, 0.f, 0.f, 0.f};
        #pragma unroll
        for (int r = 0; r < 4; ++r) { mr[m][r] = -1e30f; lr[m][r] = 0.f; }
    }

    const float* b1 = bias1 + (size_t)h * 65536;   // [q][k]
    const float* b2 = bias2 + (size_t)s * 256;
    const f16* vbase = vbT + ((size_t)s * 4 + h) * 32 * 256;

    for (int k0 = 0; k0 < 256; k0 += 32) {
        // K B-frags: B[d=8hi+j][key=lo] = K[k0+16nt+lo][d]
        h8 kf[2];
        #pragma unroll
        for (int nt = 0; nt < 2; ++nt)
            kf[nt] = *(const h8*)(kb + (rowbase + k0 + 16 * nt + lo) * 128 + h * 32 + 8 * hi);
        float b2v[2];
        #pragma unroll
        for (int nt = 0; nt < 2; ++nt) b2v[nt] = b2[k0 + 16 * nt + lo];

        f32x4 acc[4][2];
        #pragma unroll
        for (int m = 0; m < 4; ++m)
            #pragma unroll
            for (int nt = 0; nt < 2; ++nt)
                #pragma unroll
                for (int r = 0; r < 4; ++r)
                    acc[m][nt][r] = b1[(q0 + 16 * m + 4 * hi + r) * 256 + k0 + 16 * nt + lo] + b2v[nt];

        #pragma unroll
        for (int m = 0; m < 4; ++m)
            #pragma unroll
            for (int nt = 0; nt < 2; ++nt)
                acc[m][nt] = __builtin_amdgcn_mfma_f32_16x16x32_f16(qf[m], kf[nt], acc[m][nt], 0, 0, 0);

        // online softmax over this 32-key tile
        float corr[4][4];
        #pragma unroll
        for (int m = 0; m < 4; ++m) {
            #pragma unroll
            for (int r = 0; r < 4; ++r) {
                float mx = fmaxf(acc[m][0][r], acc[m][1][r]);
                #pragma unroll
                for (int wdt = 1; wdt < 16; wdt <<= 1)
                    mx = fmaxf(mx, __shfl_xor(mx, wdt, 16));
                float mn = fmaxf(mr[m][r], mx);
                corr[m][r] = __expf(mr[m][r] - mn);
                mr[m][r] = mn;
                float p0 = __expf(acc[m][0][r] - mn);
                float p1 = __expf(acc[m][1][r] - mn);
                acc[m][0][r] = p0;
                acc[m][1][r] = p1;
                float sm = p0 + p1;
                #pragma unroll
                for (int wdt = 1; wdt < 16; wdt <<= 1)
                    sm += __shfl_xor(sm, wdt, 16);
                lr[m][r] = lr[m][r] * corr[m][r] + sm;
            }
        }

        // P -> LDS (f16, swizzled). write: q=16m+4hi+r, k=nt*16+lo
        #pragma unroll
        for (int m = 0; m < 4; ++m)
            #pragma unroll
            for (int nt = 0; nt < 2; ++nt)
                #pragma unroll
                for (int r = 0; r < 4; ++r) {
                    int q = 16 * m + 4 * hi + r;
                    int swz = (nt * 2 + (lo >> 3)) ^ r ^ hi;
                    *(f16*)(pw + q * 64 + swz * 16 + (lo & 7) * 2) = (f16)acc[m][nt][r];
                }

        // rescale O
        #pragma unroll
        for (int m = 0; m < 4; ++m)
            #pragma unroll
            for (int n2 = 0; n2 < 2; ++n2)
                #pragma unroll
                for (int r = 0; r < 4; ++r)
                    Oa[m][n2][r] *= corr[m][r];

        // V B-frags: B[key=8hi+j][d=lo] = vbT[d][k0+8hi+j]
        h8 vf[2];
        #pragma unroll
        for (int n2 = 0; n2 < 2; ++n2)
            vf[n2] = *(const h8*)(vbase + (n2 * 16 + lo) * 256 + k0 + 8 * hi);

        // P A-frags + PV
        #pragma unroll
        for (int m = 0; m < 4; ++m) {
            int swz = hi ^ (lo & 3) ^ ((lo >> 2) & 3);
            h8 pa = *(const h8*)(pw + (16 * m + lo) * 64 + (swz << 4));
            #pragma unroll
            for (int n2 = 0; n2 < 2; ++n2)
                Oa[m][n2] = __builtin_amdgcn_mfma_f32_16x16x32_f16(pa, vf[n2], Oa[m][n2], 0, 0, 0);
        }
    }

    // epilogue: normalize, gate, store f16
    #pragma unroll
    for (int m = 0; m < 4; ++m) {
        #pragma unroll
        for (int r = 0; r < 4; ++r) {
            float inv = 1.f / lr[m][r];
            int qg = q0 + 16 * m + 4 * hi + r;
            #pragma unroll
            for (int n2 = 0; n2 < 2; ++n2) {
                size_t idx = (rowbase + qg) * 128 + h * 32 + n2 * 16 + lo;
                float g = (float)gb[idx];
                ob[idx] = (f16)(Oa[m][n2][r] * inv * g);
            }
        }
    }
}

// ---------------- Kernel C: output GEMM (f16 MFMA, fp32 out + bo) ----------------
__global__ __launch_bounds__(256) void out_mfma(
    const f16* __restrict__ ob, const float* __restrict__ wo,
    const float* __restrict__ bo, float* __restrict__ out)
{
    __shared__ char lds[65536];
    char* xl = lds;
    char* wl = lds + 32768;
    const int t = threadIdx.x;
    const int lane = t & 63, wave = t >> 6;
    const int wr = wave >> 1, wc = wave & 1;
    const int lo = lane & 15, hi = lane >> 4;
    const int row0 = blockIdx.x * 128;

    // stage ob tile (already f16): 16B chunks, swizzled
    #pragma unroll
    for (int j = 0; j < 8; ++j) {
        int f = t + 256 * j;
        int row = f >> 4, c8 = f & 15;
        h8 v = *(const h8*)(ob + (size_t)(row0 + row) * 128 + c8 * 8);
        *(h8*)(xl + row * 256 + ((c8 ^ (row & 7)) << 4)) = v;
    }
    // stage wo fp32 -> f16
    #pragma unroll
    for (int j = 0; j < 16; ++j) {
        int f = t + 256 * j;
        int row = f >> 5, c4 = f & 31;
        float4 v = *(const float4*)(wo + (size_t)row * 128 + c4 * 4);
        h4 hv = {(f16)v.x, (f16)v.y, (f16)v.z, (f16)v.w};
        *(h4*)(wl + row * 256 + (((c4 >> 1) ^ (row & 7)) << 4) + ((c4 & 1) << 3)) = hv;
    }
    __syncthreads();

    f32x4 acc[4][4];
    #pragma unroll
    for (int m = 0; m < 4; ++m)
        #pragma unroll
        for (int n = 0; n < 4; ++n) acc[m][n] = (f32x4){0.f, 0.f, 0.f, 0.f};

    #pragma unroll
    for (int kk = 0; kk < 4; ++kk) {
        const int swz = ((hi + 4 * kk) ^ (lo & 7)) << 4;
        h8 af[4], bf[4];
        #pragma unroll
        for (int m = 0; m < 4; ++m)
            af[m] = *(const h8*)(xl + (lo + 16 * m + 64 * wr) * 256 + swz);
        #pragma unroll
        for (int n = 0; n < 4; ++n)
            bf[n] = *(const h8*)(wl + (lo + 16 * n + 64 * wc) * 256 + swz);
        #pragma unroll
        for (int m = 0; m < 4; ++m)
            #pragma unroll
            for (int n = 0; n < 4; ++n)
                acc[m][n] = __builtin_amdgcn_mfma_f32_16x16x32_f16(af[m], bf[n], acc[m][n], 0, 0, 0);
    }

    #pragma unroll
    for (int n = 0; n < 4; ++n) {
        const int col = 64 * wc + 16 * n + lo;
        const float bov = bo[col];
        #pragma unroll
        for (int m = 0; m < 4; ++m)
            #pragma unroll
            for (int r = 0; r < 4; ++r)
                out[(size_t)(row0 + 64 * wr + 16 * m + 4 * hi + r) * 128 + col] = acc[m][n][r] + bov;
    }
}

extern "C" void kernel_launch(void* const* d_in, const int* in_sizes, int n_in,
                              void* d_out, int out_size, void* d_ws, size_t ws_size,
                              hipStream_t stream)
{
    const float* q_x   = (const float*)d_in[0];
    const float* kv_x  = (const float*)d_in[1];
    const float* bias1 = (const float*)d_in[2];
    const float* bias2 = (const float*)d_in[3];
    const float* wq    = (const float*)d_in[4];
    const float* wk    = (const float*)d_in[5];
    const float* wv    = (const float*)d_in[6];
    const float* wg    = (const float*)d_in[7];
    const float* bg    = (const float*)d_in[8];
    const float* wo    = (const float*)d_in[9];
    const float* bo    = (const float*)d_in[10];
    float* out = (float*)d_out;

    const size_t RC = (size_t)65536 * 128;
    f16* ws  = (f16*)d_ws;
    f16* qb  = ws;
    f16* kb  = ws + RC;
    f16* vbT = ws + 2 * RC;
    f16* gb  = ws + 3 * RC;
    f16* ob  = ws + 4 * RC;

    proj_mfma<<<dim3(512, 2), 256, 0, stream>>>(q_x, kv_x, wq, wk, wv, wg, bg, qb, kb, vbT, gb);
    attn_mfma<<<dim3(4, 256), 256, 0, stream>>>(qb, kb, vbT, gb, bias1, bias2, ob);
    out_mfma<<<512, 256, 0, stream>>>(ob, wo, bo, out);
}